// Round 13
// baseline (150.108 us; speedup 1.0000x reference)
//
#include <hip/hip_runtime.h>
#include <hip/hip_bf16.h>
#include <cstdint>
#include <cstddef>

#define TB 4
#define TC 512
#define TT 2304
#define TH 16
#define TD 32
#define TW 19
#define WOVR 9
#define EPSLN 1e-5f
#define SCALE 0.17677669529663687f   // 1/sqrt(32)
#define MTOT (TB * TT)               // 9216 rows
#define KSZ  512

typedef __attribute__((ext_vector_type(8))) short s16x8;
typedef __attribute__((ext_vector_type(8))) unsigned short u16x8;
typedef __attribute__((ext_vector_type(4))) float f32x4;

__device__ __forceinline__ float bf2f(unsigned short u) {
  union { unsigned int i; float f; } x; x.i = ((unsigned int)u) << 16; return x.f;
}
__device__ __forceinline__ unsigned short f2bf(float f) {
  union { __hip_bfloat16 h; unsigned short u; } c;
  c.h = __float2bfloat16(f);
  return c.u;
}
__device__ __forceinline__ float mval(const unsigned char* mraw, int idx) {
  const uint32_t w0 = *(const uint32_t*)mraw;
  bool on;
  if (w0 == 1u)                 on = ((const int*)mraw)[idx] != 0;
  else if (w0 == 0x01010101u)   on = mraw[idx] != 0;
  else                          on = ((const float*)mraw)[idx] != 0.0f;
  return on ? 1.0f : 0.0f;
}

// ---- fused: prep (weights->bf16, mask->mf+tail) + 3x (conv3+mask+LN(C)) ----
// PROVEN R12 version (byte-identical).
__global__ __launch_bounds__(512) void k_conv_ln_t(
    const float* __restrict__ x,
    const float* __restrict__ wq, const float* __restrict__ wk, const float* __restrict__ wv,
    const float* __restrict__ gq, const float* __restrict__ bq,
    const float* __restrict__ gk, const float* __restrict__ bk,
    const float* __restrict__ gv, const float* __restrict__ bv,
    const float* __restrict__ wquery, const float* __restrict__ wkey,
    const float* __restrict__ wvalue, const float* __restrict__ wproj,
    const unsigned char* __restrict__ mraw,
    unsigned short* __restrict__ Wbf, float* __restrict__ mf,
    float* __restrict__ outtail, unsigned short* __restrict__ Aall) {
  const int b = blockIdx.y;
  const int t0 = blockIdx.x * 16;
  const int tid = threadIdx.x;
  const int tt = tid & 15, cg = tid >> 4;   // cg in [0,32), 16 channels each

  // ---- merged prep: weight pack + mask expand (grid-strided, 576x512) ----
  {
    const int gtid = (b * 144 + blockIdx.x) * 512 + tid;   // 294912 total
    #pragma unroll
    for (int rep = 0; rep < 4; rep++) {
      const int j = gtid + rep * 294912;
      if (j < 4 * TC * TC) {
        const int zz = j >> 18, r = j & (TC * TC - 1);
        const float* src = (zz == 0) ? wquery : (zz == 1) ? wkey
                          : (zz == 2) ? wvalue : wproj;
        Wbf[j] = f2bf(src[r]);
      }
    }
    if (gtid < TB * TT) {
      const float v = mval(mraw, gtid);
      mf[gtid] = v;
      outtail[(size_t)TB * TC * TT + gtid] = v;   // tuple output #2
    }
  }

  __shared__ float4 wlds[3][544];           // (w0,w1,w2,-) per channel, padded
  __shared__ float2 gblds[3][544];          // (gamma,beta) per channel, padded
  __shared__ float ps[3][32][17], ps2[3][32][17];
  __shared__ float mean_s[3][16], rstd_s[3][16];

  {
    const int c = tid, cp = c + (c >> 4);
    wlds[0][cp] = make_float4(wq[c*3], wq[c*3+1], wq[c*3+2], 0.f);
    wlds[1][cp] = make_float4(wk[c*3], wk[c*3+1], wk[c*3+2], 0.f);
    wlds[2][cp] = make_float4(wv[c*3], wv[c*3+1], wv[c*3+2], 0.f);
    gblds[0][cp] = make_float2(gq[c], bq[c]);
    gblds[1][cp] = make_float2(gk[c], bk[c]);
    gblds[2][cp] = make_float2(gv[c], bv[c]);
  }
  __syncthreads();

  const int tg = t0 + tt;
  const float m = mval(mraw, b * TT + tg);
  const int tm = tg > 0 ? tg - 1 : 0;
  const int tp = tg < TT - 1 ? tg + 1 : TT - 1;
  const float zl = (tg > 0) ? 1.f : 0.f;        // zero-pad left edge
  const float zr = (tg < TT - 1) ? 1.f : 0.f;   // zero-pad right edge

  const float* xb = x + ((size_t)(b * TC + cg * 16)) * TT;
  float xm[16], x0[16], xp[16];
  #pragma unroll
  for (int i = 0; i < 16; i++) {
    const float* xc = xb + (size_t)i * TT;
    xm[i] = xc[tm]; x0[i] = xc[tg]; xp[i] = xc[tp];
  }

  float s[3] = {}, s2[3] = {};
  unsigned int yp[3][8];
  #pragma unroll
  for (int i = 0; i < 16; i++) {
    const int cp = cg * 17 + i;
    const float xml = xm[i] * zl, xpl = xp[i] * zr;
    #pragma unroll
    for (int z = 0; z < 3; z++) {
      const float4 w = wlds[z][cp];
      const float y = (w.x * xml + w.y * x0[i] + w.z * xpl) * m;
      s[z] += y; s2[z] += y * y;
      const unsigned int h = f2bf(y);
      if ((i & 1) == 0) yp[z][i >> 1] = h;
      else              yp[z][i >> 1] |= h << 16;
    }
  }
  #pragma unroll
  for (int z = 0; z < 3; z++) {
    ps[z][cg][tt] = s[z]; ps2[z][cg][tt] = s2[z];
  }
  __syncthreads();
  if (tid < 48) {
    const int z = tid >> 4, tl = tid & 15;
    float su = 0.f, su2 = 0.f;
    #pragma unroll
    for (int g = 0; g < 32; g++) { su += ps[z][g][tl]; su2 += ps2[z][g][tl]; }
    const float mean = su * (1.f / TC);
    const float var  = su2 * (1.f / TC) - mean * mean;
    mean_s[z][tl] = mean;
    rstd_s[z][tl] = rsqrtf(fmaxf(var, 0.f) + EPSLN);
  }
  __syncthreads();

  #pragma unroll
  for (int z = 0; z < 3; z++) {
    const float mean = mean_s[z][tt], rs = rstd_s[z][tt];
    unsigned short tmp[16];
    #pragma unroll
    for (int i = 0; i < 16; i++) {
      const float2 gb = gblds[z][cg * 17 + i];
      const unsigned short hb = (unsigned short)(
          (i & 1) ? (yp[z][i >> 1] >> 16) : (yp[z][i >> 1] & 0xffffu));
      tmp[i] = f2bf((bf2f(hb) - mean) * rs * gb.x + gb.y);
    }
    unsigned short* oz = Aall + ((size_t)z * MTOT + b * TT + tg) * TC + cg * 16;
    *(u16x8*)(oz)     = *(const u16x8*)(tmp);
    *(u16x8*)(oz + 8) = *(const u16x8*)(tmp + 8);
  }
}

// ------- MFMA GEMM, REG-DIRECT (no LDS, no barriers, no inline waitcnt) -----
// 128x128 block tile, 4 waves (2x2), wave tile 64x64. Fragments are loaded
// global->VGPR directly (canonical layout: lane l loads 16B at
// [row = base + i*16 + (l&15)][k0 + (l>>4)*8]). Double-buffered register
// sets, statically indexed via full unroll. Each wave fully independent:
// zero race surface; compiler inserts counted vmcnt automatically.
// Operands swapped in mfma: D lane-dim = bt rows, reg-dim = channels.
template<int F32OUT>
__global__ __launch_bounds__(256) void k_gemm_reg(
    const unsigned short* __restrict__ Abase, const unsigned short* __restrict__ Wbase,
    const float* __restrict__ bq, const float* __restrict__ bk, const float* __restrict__ bv,
    unsigned short* __restrict__ obf, float* __restrict__ of32,
    const float* __restrict__ mf) {
  const int nw = gridDim.x;                       // multiple of 8
  int w = blockIdx.x;
  w = (w & 7) * (nw >> 3) + (w >> 3);             // chunked XCD swizzle
  const int z = w / 288;                          // 288 = 72 m-tiles * 4 n-tiles
  const int rem = w - z * 288;
  const int m0 = (rem >> 2) * 128;
  const int n0 = (rem & 3) * 128;

  const unsigned short* A = Abase + (size_t)z * MTOT * KSZ;
  const unsigned short* W = Wbase + (size_t)z * KSZ * KSZ;
  const float* bias = (z == 0) ? bq : (z == 1) ? bk : bv;

  const int tid = threadIdx.x;
  const int l = tid & 63, l15 = l & 15, l4 = l >> 4;
  const int wid = tid >> 6, wm = wid >> 1, wn = wid & 1;

  const unsigned short* pa[4];
  const unsigned short* pb[4];
  #pragma unroll
  for (int i = 0; i < 4; i++) {
    pa[i] = A + (size_t)(m0 + wm * 64 + i * 16 + l15) * KSZ + l4 * 8;
    pb[i] = W + (size_t)(n0 + wn * 64 + i * 16 + l15) * KSZ + l4 * 8;
  }

  f32x4 acc[4][4] = {};
  s16x8 av[2][4], bw[2][4];
  #pragma unroll
  for (int i = 0; i < 4; i++) {
    av[0][i] = *(const s16x8*)(pa[i]);
    bw[0][i] = *(const s16x8*)(pb[i]);
  }
  #pragma unroll
  for (int t = 0; t < 16; ++t) {
    const int cur = t & 1, nxt = cur ^ 1;   // compile-time after unroll
    if (t + 1 < 16) {
      #pragma unroll
      for (int i = 0; i < 4; i++) {
        av[nxt][i] = *(const s16x8*)(pa[i] + (t + 1) * 32);
        bw[nxt][i] = *(const s16x8*)(pb[i] + (t + 1) * 32);
      }
    }
    __builtin_amdgcn_s_setprio(1);
    #pragma unroll
    for (int mi = 0; mi < 4; mi++)
      #pragma unroll
      for (int nj = 0; nj < 4; nj++)
        acc[mi][nj] = __builtin_amdgcn_mfma_f32_16x16x32_bf16(
            bw[cur][nj], av[cur][mi], acc[mi][nj], 0, 0, 0);
    __builtin_amdgcn_s_setprio(0);
  }

  if (!F32OUT) {
    // bf16 out [bt][512]: lane holds 4 consecutive channels -> 8B packed store
    unsigned short* O = obf + (size_t)z * MTOT * KSZ;
    #pragma unroll
    for (int nj = 0; nj < 4; nj++) {
      const int ch0 = n0 + wn * 64 + nj * 16 + l4 * 4;
      const float4 bi = *(const float4*)&bias[ch0];
      #pragma unroll
      for (int mi = 0; mi < 4; mi++) {
        const int bt = m0 + wm * 64 + mi * 16 + l15;
        uint2 pk;
        pk.x = (uint32_t)f2bf(acc[mi][nj][0] + bi.x) |
               ((uint32_t)f2bf(acc[mi][nj][1] + bi.y) << 16);
        pk.y = (uint32_t)f2bf(acc[mi][nj][2] + bi.z) |
               ((uint32_t)f2bf(acc[mi][nj][3] + bi.w) << 16);
        *(uint2*)&O[(size_t)bt * KSZ + ch0] = pk;
      }
    }
  } else {
    // f32 out [B][C][T] with fused mask; lanes span 16 consecutive t
    const int bb = m0 / TT;
    const int tl0 = m0 - bb * TT;
    #pragma unroll
    for (int mi = 0; mi < 4; mi++) {
      const int bt = m0 + wm * 64 + mi * 16 + l15;
      const int tloc = tl0 + wm * 64 + mi * 16 + l15;
      const float mm = mf[bt];
      #pragma unroll
      for (int nj = 0; nj < 4; nj++) {
        const int ch0 = n0 + wn * 64 + nj * 16 + l4 * 4;
        const float4 bi = *(const float4*)&bias[ch0];
        #pragma unroll
        for (int r = 0; r < 4; r++) {
          const float biv = r == 0 ? bi.x : r == 1 ? bi.y : r == 2 ? bi.z : bi.w;
          of32[((size_t)(bb * TC + ch0 + r)) * TT + tloc] =
              (acc[mi][nj][r] + biv) * mm;
        }
      }
    }
  }
}

// ---------------- banded attention, LDS-staged K/V, d-split x2 ----------------
#define AROWS (128 + 2 * WOVR)   // 146
#define ASTR  36                 // 32 data + 4 pad ushorts = 72B rows
__global__ __launch_bounds__(256) void k_attn_lds(
    const unsigned short* __restrict__ QKV, const float* __restrict__ mf,
    unsigned short* __restrict__ AO) {
  const int t0 = blockIdx.x * 128;
  const int h = blockIdx.y, b = blockIdx.z;
  const int tid = threadIdx.x;
  const int tloc = tid >> 1, half = tid & 1;
  const size_t SZ = (size_t)MTOT * KSZ;
  const unsigned short* Qp = QKV;
  const unsigned short* Kp = QKV + SZ;
  const unsigned short* Vp = QKV + 2 * SZ;
  __shared__ unsigned short Ks[AROWS * ASTR], Vs[AROWS * ASTR];
  __shared__ float mfs[AROWS];

  for (int idx = tid; idx < 2 * AROWS * 4; idx += 256) {
    const int bufv = idx >= AROWS * 4;
    const int ci = idx - bufv * AROWS * 4;
    const int r = ci >> 2, c = ci & 3;
    const int tk = t0 - WOVR + r;
    const int tkc = tk < 0 ? 0 : (tk >= TT ? TT - 1 : tk);
    const unsigned short* src =
        (bufv ? Vp : Kp) + ((size_t)(b * TT + tkc)) * TC + h * TD + c * 8;
    uint4 v = *(const uint4*)src;
    unsigned short* dst = (bufv ? Vs : Ks) + r * ASTR + c * 8;
    uint2 lo; lo.x = v.x; lo.y = v.y;
    uint2 hi; hi.x = v.z; hi.y = v.w;
    *(uint2*)dst = lo; *(uint2*)(dst + 4) = hi;
  }
  if (tid < AROWS) {
    const int tk = t0 - WOVR + tid;
    mfs[tid] = (tk >= 0 && tk < TT) ? (mf[b * TT + tk] != 0.f ? 0.f : -1e4f)
                                    : -1e30f;
  }
  __syncthreads();

  const int t = t0 + tloc;
  const float qm = mf[b * TT + t];
  float q[16];
  {
    const unsigned short* qr = Qp + ((size_t)(b * TT + t)) * TC + h * TD + half * 16;
    #pragma unroll
    for (int c = 0; c < 2; c++) {
      u16x8 v = *(const u16x8*)(qr + c * 8);
      #pragma unroll
      for (int j = 0; j < 8; j++) q[c * 8 + j] = bf2f(v[j]);
    }
  }
  float e[TW];
  float smax = -3.0e38f;
  #pragma unroll
  for (int j = 0; j < TW; j++) {
    const unsigned short* kr = Ks + (tloc + j) * ASTR + half * 16;
    float acc = 0.f;
    #pragma unroll
    for (int c = 0; c < 4; c++) {
      uint2 w = *(const uint2*)(kr + c * 4);
      acc = fmaf(q[c*4+0], bf2f((unsigned short)(w.x & 0xffffu)), acc);
      acc = fmaf(q[c*4+1], bf2f((unsigned short)(w.x >> 16)), acc);
      acc = fmaf(q[c*4+2], bf2f((unsigned short)(w.y & 0xffffu)), acc);
      acc = fmaf(q[c*4+3], bf2f((unsigned short)(w.y >> 16)), acc);
    }
    acc += __shfl_xor(acc, 1, 64);
    const float sv = acc * SCALE + mfs[tloc + j];
    e[j] = sv;
    smax = fmaxf(smax, sv);
  }
  float den = 0.f;
  #pragma unroll
  for (int j = 0; j < TW; j++) { const float ev = __expf(e[j] - smax); e[j] = ev; den += ev; }
  float o[16] = {};
  #pragma unroll
  for (int j = 0; j < TW; j++) {
    const unsigned short* vr = Vs + (tloc + j) * ASTR + half * 16;
    const float p = e[j];
    #pragma unroll
    for (int c = 0; c < 4; c++) {
      uint2 w = *(const uint2*)(vr + c * 4);
      o[c*4+0] = fmaf(p, bf2f((unsigned short)(w.x & 0xffffu)), o[c*4+0]);
      o[c*4+1] = fmaf(p, bf2f((unsigned short)(w.x >> 16)), o[c*4+1]);
      o[c*4+2] = fmaf(p, bf2f((unsigned short)(w.y & 0xffffu)), o[c*4+2]);
      o[c*4+3] = fmaf(p, bf2f((unsigned short)(w.y >> 16)), o[c*4+3]);
    }
  }
  const float sc = qm / den;
  unsigned short tmp[16];
  #pragma unroll
  for (int i = 0; i < 16; i++) tmp[i] = f2bf(o[i] * sc);
  unsigned short* op = AO + ((size_t)(b * TT + t)) * TC + h * TD + half * 16;
  *(u16x8*)(op)     = *(const u16x8*)(tmp);
  *(u16x8*)(op + 8) = *(const u16x8*)(tmp + 8);
}

extern "C" void kernel_launch(void* const* d_in, const int* in_sizes, int n_in,
                              void* d_out, int out_size, void* d_ws, size_t ws_size,
                              hipStream_t stream) {
  const float* x       = (const float*)d_in[0];
  const float* w_qconv = (const float*)d_in[1];
  const float* w_kconv = (const float*)d_in[2];
  const float* w_vconv = (const float*)d_in[3];
  const float* g_q = (const float*)d_in[4];
  const float* b_q = (const float*)d_in[5];
  const float* g_k = (const float*)d_in[6];
  const float* b_k = (const float*)d_in[7];
  const float* g_v = (const float*)d_in[8];
  const float* b_v = (const float*)d_in[9];
  const float* w_query = (const float*)d_in[10];
  const float* b_query = (const float*)d_in[11];
  const float* w_key   = (const float*)d_in[12];
  const float* b_key   = (const float*)d_in[13];
  const float* w_value = (const float*)d_in[14];
  const float* b_value = (const float*)d_in[15];
  const float* w_proj  = (const float*)d_in[16];
  const float* b_proj  = (const float*)d_in[17];
  const unsigned char* mraw = (const unsigned char*)d_in[18];
  float* out = (float*)d_out;

  uint8_t* w8 = (uint8_t*)d_ws;
  float* mf            = (float*)w8;                                   // 36 KB
  unsigned short* Wbf  = (unsigned short*)(w8 + (1ull << 20));         // 2 MB
  unsigned short* Aall = (unsigned short*)(w8 + (4ull << 20));         // 28.3 MB
  unsigned short* QKV  = (unsigned short*)(w8 + (34ull << 20));        // 28.3 MB
  unsigned short* AO   = (unsigned short*)(w8 + (63ull << 20));        // 9.4 MB

  k_conv_ln_t<<<dim3(144, TB), dim3(512), 0, stream>>>(
      x, w_qconv, w_kconv, w_vconv, g_q, b_q, g_k, b_k, g_v, b_v,
      w_query, w_key, w_value, w_proj, mraw, Wbf, mf, out, Aall);
  k_gemm_reg<0><<<dim3(864), dim3(256), 0, stream>>>(
      Aall, Wbf, b_query, b_key, b_value, QKV, nullptr, mf);
  k_attn_lds<<<dim3(TT / 128, TH, TB), dim3(256), 0, stream>>>(QKV, mf, AO);
  k_gemm_reg<1><<<dim3(288), dim3(256), 0, stream>>>(
      AO, Wbf + 3 * TC * TC, b_proj, b_proj, b_proj, nullptr, out, mf);
}

// Round 14
// 97.196 us; speedup vs baseline: 1.5444x; 1.5444x over previous
//
#include <hip/hip_runtime.h>
#include <hip/hip_bf16.h>
#include <cstdint>
#include <cstddef>

#define TB 4
#define TC 512
#define TT 2304
#define TH 16
#define TD 32
#define TW 19
#define WOVR 9
#define EPSLN 1e-5f
#define SCALE 0.17677669529663687f   // 1/sqrt(32)
#define MTOT (TB * TT)               // 9216 rows
#define KSZ  512

typedef __attribute__((ext_vector_type(8))) short s16x8;
typedef __attribute__((ext_vector_type(8))) unsigned short u16x8;
typedef __attribute__((ext_vector_type(4))) float f32x4;

__device__ __forceinline__ float bf2f(unsigned short u) {
  union { unsigned int i; float f; } x; x.i = ((unsigned int)u) << 16; return x.f;
}
__device__ __forceinline__ unsigned short f2bf(float f) {
  union { __hip_bfloat16 h; unsigned short u; } c;
  c.h = __float2bfloat16(f);
  return c.u;
}
__device__ __forceinline__ void gload16(const void* g, void* l) {
  __builtin_amdgcn_global_load_lds(
      (const __attribute__((address_space(1))) unsigned int*)g,
      (__attribute__((address_space(3))) unsigned int*)l, 16, 0, 0);
}
__device__ __forceinline__ float mval(const unsigned char* mraw, int idx) {
  const uint32_t w0 = *(const uint32_t*)mraw;
  bool on;
  if (w0 == 1u)                 on = ((const int*)mraw)[idx] != 0;
  else if (w0 == 0x01010101u)   on = mraw[idx] != 0;
  else                          on = ((const float*)mraw)[idx] != 0.0f;
  return on ? 1.0f : 0.0f;
}

// ---- fused: prep (weights->bf16, mask->mf+tail) + 3x (conv3+mask+LN(C)) ----
// LOAD PHASE: thread = channel; 4 aligned float4 + 2 halo scalars cover the
// 18-float t-row (6 VMEM instr vs 48 scalars). Conv in registers with the
// thread's own 9 weights. LDS transpose ys[512][16] -> (t,cgroup) layout for
// LN reduce + coalesced bf16 store. 3 barriers per z (hazard-checked).
__global__ __launch_bounds__(512) void k_conv_ln_t(
    const float* __restrict__ x,
    const float* __restrict__ wq, const float* __restrict__ wk, const float* __restrict__ wv,
    const float* __restrict__ gq, const float* __restrict__ bq,
    const float* __restrict__ gk, const float* __restrict__ bk,
    const float* __restrict__ gv, const float* __restrict__ bv,
    const float* __restrict__ wquery, const float* __restrict__ wkey,
    const float* __restrict__ wvalue, const float* __restrict__ wproj,
    const unsigned char* __restrict__ mraw,
    unsigned short* __restrict__ Wbf, float* __restrict__ mf,
    float* __restrict__ outtail, unsigned short* __restrict__ Aall) {
  const int b = blockIdx.y;
  const int t0 = blockIdx.x * 16;
  const int tid = threadIdx.x;
  const int tt = tid & 15, cg = tid >> 4;   // cg in [0,32), 16 channels each

  // ---- merged prep: weight pack + mask expand (grid-strided, 576x512) ----
  {
    const int gtid = (b * 144 + blockIdx.x) * 512 + tid;   // 294912 total
    #pragma unroll
    for (int rep = 0; rep < 4; rep++) {
      const int j = gtid + rep * 294912;
      if (j < 4 * TC * TC) {
        const int zz = j >> 18, r = j & (TC * TC - 1);
        const float* src = (zz == 0) ? wquery : (zz == 1) ? wkey
                          : (zz == 2) ? wvalue : wproj;
        Wbf[j] = f2bf(src[r]);
      }
    }
    if (gtid < TB * TT) {
      const float v = mval(mraw, gtid);
      mf[gtid] = v;
      outtail[(size_t)TB * TC * TT + gtid] = v;   // tuple output #2
    }
  }

  __shared__ float ys[512][16];             // 32KB, one z at a time
  __shared__ float ps[32][17], ps2[32][17]; // 4.4KB
  __shared__ float mean_s[16], rstd_s[16];
  __shared__ float2 gblds[3][544];          // 13KB (gamma,beta), padded

  {
    const int c = tid, cp = c + (c >> 4);
    gblds[0][cp] = make_float2(gq[c], bq[c]);
    gblds[1][cp] = make_float2(gk[c], bk[c]);
    gblds[2][cp] = make_float2(gv[c], bv[c]);
  }

  // ---- load phase: this thread's channel row, 18 floats ----
  const float* xc = x + ((size_t)(b * TC + tid)) * TT;
  float xr[18];
  {
    const float4 v0 = *(const float4*)&xc[t0];
    const float4 v1 = *(const float4*)&xc[t0 + 4];
    const float4 v2 = *(const float4*)&xc[t0 + 8];
    const float4 v3 = *(const float4*)&xc[t0 + 12];
    xr[1] = v0.x;  xr[2] = v0.y;  xr[3] = v0.z;  xr[4] = v0.w;
    xr[5] = v1.x;  xr[6] = v1.y;  xr[7] = v1.z;  xr[8] = v1.w;
    xr[9] = v2.x;  xr[10] = v2.y; xr[11] = v2.z; xr[12] = v2.w;
    xr[13] = v3.x; xr[14] = v3.y; xr[15] = v3.z; xr[16] = v3.w;
    xr[0]  = (t0 > 0)       ? xc[t0 - 1]  : 0.f;
    xr[17] = (t0 + 16 < TT) ? xc[t0 + 16] : 0.f;
  }
  float mk[16];
  #pragma unroll
  for (int j = 0; j < 16; j++) mk[j] = mval(mraw, b * TT + t0 + j);
  float wcv[3][3];
  #pragma unroll
  for (int k = 0; k < 3; k++) {
    wcv[0][k] = wq[tid * 3 + k];
    wcv[1][k] = wk[tid * 3 + k];
    wcv[2][k] = wv[tid * 3 + k];
  }

  for (int z = 0; z < 3; z++) {
    // conv (registers only)
    float y[16];
    #pragma unroll
    for (int j = 0; j < 16; j++)
      y[j] = (wcv[z][0] * xr[j] + wcv[z][1] * xr[j + 1] +
              wcv[z][2] * xr[j + 2]) * mk[j];
    // transpose via LDS: aligned b128 writes
    #pragma unroll
    for (int q = 0; q < 4; q++)
      *(float4*)&ys[tid][q * 4] =
          make_float4(y[q * 4], y[q * 4 + 1], y[q * 4 + 2], y[q * 4 + 3]);
    __syncthreads();
    // partial sums: thread (tt,cg) over its 16 channels at column tt
    float yv[16], su = 0.f, su2 = 0.f;
    #pragma unroll
    for (int i = 0; i < 16; i++) {
      const float v = ys[cg * 16 + i][tt];
      yv[i] = v; su += v; su2 += v * v;
    }
    ps[cg][tt] = su; ps2[cg][tt] = su2;
    __syncthreads();
    if (tid < 16) {
      float s1 = 0.f, s2 = 0.f;
      #pragma unroll
      for (int g = 0; g < 32; g++) { s1 += ps[g][tid]; s2 += ps2[g][tid]; }
      const float mean = s1 * (1.f / TC);
      const float var  = s2 * (1.f / TC) - mean * mean;
      mean_s[tid] = mean;
      rstd_s[tid] = rsqrtf(fmaxf(var, 0.f) + EPSLN);
    }
    __syncthreads();
    // write phase: LN transform + coalesced 32B bf16 store
    const float mean = mean_s[tt], rs = rstd_s[tt];
    unsigned short tmp[16];
    #pragma unroll
    for (int i = 0; i < 16; i++) {
      const int c = cg * 16 + i;
      const float2 gb = gblds[z][c + (c >> 4)];
      tmp[i] = f2bf((yv[i] - mean) * rs * gb.x + gb.y);
    }
    unsigned short* oz =
        Aall + ((size_t)z * MTOT + b * TT + t0 + tt) * TC + cg * 16;
    *(u16x8*)(oz)     = *(const u16x8*)(tmp);
    *(u16x8*)(oz + 8) = *(const u16x8*)(tmp + 8);
    __syncthreads();   // ys/ps reuse next z (write-after-read ordering)
  }
}

// ---------------- MFMA GEMM: D[m][n] = sum_k A[m][k] * W[n][k] (+bias[n]) ----
// PROVEN R12 schedule (byte-identical): 128x128 tile, 4 waves (2x2), 3-stage
// LDS pipeline, counted vmcnt; ONE combined "s_waitcnt vmcnt(N) lgkmcnt(0);
// s_barrier" per K-step. s_setprio around MFMA cluster. Operands swapped in
// mfma so D lane-dim = bt rows, reg-dim = channels.
template<int F32OUT>
__global__ __launch_bounds__(256) void k_gemm_mfma(
    const unsigned short* __restrict__ Abase, const unsigned short* __restrict__ Wbase,
    const float* __restrict__ bq, const float* __restrict__ bk, const float* __restrict__ bv,
    unsigned short* __restrict__ obf, float* __restrict__ of32,
    const float* __restrict__ mf) {
  const int nw = gridDim.x;                       // multiple of 8
  int w = blockIdx.x;
  w = (w & 7) * (nw >> 3) + (w >> 3);             // chunked XCD swizzle
  const int z = w / 288;                          // 288 = 72 m-tiles * 4 n-tiles
  const int rem = w - z * 288;
  const int m0 = (rem >> 2) * 128;
  const int n0 = (rem & 3) * 128;

  const unsigned short* A = Abase + (size_t)z * MTOT * KSZ;
  const unsigned short* W = Wbase + (size_t)z * KSZ * KSZ;
  const float* bias = (z == 0) ? bq : (z == 1) ? bk : bv;

  // 3 A-buffers then 3 B-buffers, each 128x32 bf16 = 8KB; total 48KB
  __shared__ __align__(16) unsigned short smem[6 * 4096];
  const int tid = threadIdx.x;
  const int l = tid & 63, l15 = l & 15, l4 = l >> 4;
  const int wid = tid >> 6, wm = wid >> 1, wn = wid & 1;

  const int r0 = tid >> 2;
  const int c0 = (tid & 3) ^ ((r0 >> 1) & 3);
  const int r1 = r0 + 64;
  const int c1 = (tid & 3) ^ ((r1 >> 1) & 3);
  const size_t gaA0 = (size_t)(m0 + r0) * KSZ + c0 * 8;
  const size_t gaA1 = (size_t)(m0 + r1) * KSZ + c1 * 8;
  const size_t gaB0 = (size_t)(n0 + r0) * KSZ + c0 * 8;
  const size_t gaB1 = (size_t)(n0 + r1) * KSZ + c1 * 8;

  int offA[4], offB[4];
  #pragma unroll
  for (int i = 0; i < 4; i++) {
    const int ra = wm * 64 + i * 16 + l15;
    offA[i] = (ra * 4 + (l4 ^ ((ra >> 1) & 3))) * 8;
    const int rb = wn * 64 + i * 16 + l15;
    offB[i] = (rb * 4 + (l4 ^ ((rb >> 1) & 3))) * 8;
  }

  #define STAGE(buf, kk)                                           \
    do {                                                           \
      unsigned short* Ad = smem + (buf) * 4096;                    \
      unsigned short* Bd = smem + 3 * 4096 + (buf) * 4096;         \
      gload16(A + gaA0 + (kk), Ad + tid * 8);                      \
      gload16(A + gaA1 + (kk), Ad + (tid + 256) * 8);              \
      gload16(W + gaB0 + (kk), Bd + tid * 8);                      \
      gload16(W + gaB1 + (kk), Bd + (tid + 256) * 8);              \
    } while (0)

  f32x4 acc[4][4] = {};
  STAGE(0, 0);
  STAGE(1, 32);
  // tile0 landed (my 4 oldest of 8 outstanding), all threads synced
  asm volatile("s_waitcnt vmcnt(4)\ns_barrier" ::: "memory");

  #pragma unroll
  for (int t = 0; t < 16; ++t) {
    if (t + 2 < 16) STAGE((t + 2) % 3, (t + 2) * 32);
    const unsigned short* Ac = smem + (t % 3) * 4096;
    const unsigned short* Bc = smem + 3 * 4096 + (t % 3) * 4096;
    s16x8 av[4], bw[4];
    #pragma unroll
    for (int i = 0; i < 4; i++) {
      av[i] = *(const s16x8*)(Ac + offA[i]);
      bw[i] = *(const s16x8*)(Bc + offB[i]);
    }
    __builtin_amdgcn_s_setprio(1);
    #pragma unroll
    for (int mi = 0; mi < 4; mi++)
      #pragma unroll
      for (int nj = 0; nj < 4; nj++)
        acc[mi][nj] = __builtin_amdgcn_mfma_f32_16x16x32_bf16(
            bw[nj], av[mi], acc[mi][nj], 0, 0, 0);   // swapped: D reg-dim = ch
    __builtin_amdgcn_s_setprio(0);
    // lgkmcnt(0): my ds_reads done (no overwrite race); vmcnt(4): tile t+1
    // landed (4 loads for t+2 still in flight); s_barrier: all threads agree.
    if (t < 14)
      asm volatile("s_waitcnt vmcnt(4) lgkmcnt(0)\ns_barrier" ::: "memory");
    else if (t == 14)
      asm volatile("s_waitcnt vmcnt(0) lgkmcnt(0)\ns_barrier" ::: "memory");
  }
  #undef STAGE

  if (!F32OUT) {
    // bf16 out [bt][512]: lane holds 4 consecutive channels -> 8B packed store
    unsigned short* O = obf + (size_t)z * MTOT * KSZ;
    #pragma unroll
    for (int nj = 0; nj < 4; nj++) {
      const int ch0 = n0 + wn * 64 + nj * 16 + l4 * 4;
      const float4 bi = *(const float4*)&bias[ch0];
      #pragma unroll
      for (int mi = 0; mi < 4; mi++) {
        const int bt = m0 + wm * 64 + mi * 16 + l15;
        uint2 pk;
        pk.x = (uint32_t)f2bf(acc[mi][nj][0] + bi.x) |
               ((uint32_t)f2bf(acc[mi][nj][1] + bi.y) << 16);
        pk.y = (uint32_t)f2bf(acc[mi][nj][2] + bi.z) |
               ((uint32_t)f2bf(acc[mi][nj][3] + bi.w) << 16);
        *(uint2*)&O[(size_t)bt * KSZ + ch0] = pk;
      }
    }
  } else {
    // f32 out [B][C][T] with fused mask; lanes span 16 consecutive t
    const int bb = m0 / TT;
    const int tl0 = m0 - bb * TT;
    #pragma unroll
    for (int mi = 0; mi < 4; mi++) {
      const int bt = m0 + wm * 64 + mi * 16 + l15;
      const int tloc = tl0 + wm * 64 + mi * 16 + l15;
      const float mm = mf[bt];
      #pragma unroll
      for (int nj = 0; nj < 4; nj++) {
        const int ch0 = n0 + wn * 64 + nj * 16 + l4 * 4;
        const float4 bi = *(const float4*)&bias[ch0];
        #pragma unroll
        for (int r = 0; r < 4; r++) {
          const float biv = r == 0 ? bi.x : r == 1 ? bi.y : r == 2 ? bi.z : bi.w;
          of32[((size_t)(bb * TC + ch0 + r)) * TT + tloc] =
              (acc[mi][nj][r] + biv) * mm;
        }
      }
    }
  }
}

// ---------------- banded attention, LDS-staged K/V, d-split x2 ----------------
#define AROWS (128 + 2 * WOVR)   // 146
#define ASTR  36                 // 32 data + 4 pad ushorts = 72B rows
__global__ __launch_bounds__(256) void k_attn_lds(
    const unsigned short* __restrict__ QKV, const float* __restrict__ mf,
    unsigned short* __restrict__ AO) {
  const int t0 = blockIdx.x * 128;
  const int h = blockIdx.y, b = blockIdx.z;
  const int tid = threadIdx.x;
  const int tloc = tid >> 1, half = tid & 1;
  const size_t SZ = (size_t)MTOT * KSZ;
  const unsigned short* Qp = QKV;
  const unsigned short* Kp = QKV + SZ;
  const unsigned short* Vp = QKV + 2 * SZ;
  __shared__ unsigned short Ks[AROWS * ASTR], Vs[AROWS * ASTR];
  __shared__ float mfs[AROWS];

  for (int idx = tid; idx < 2 * AROWS * 4; idx += 256) {
    const int bufv = idx >= AROWS * 4;
    const int ci = idx - bufv * AROWS * 4;
    const int r = ci >> 2, c = ci & 3;
    const int tk = t0 - WOVR + r;
    const int tkc = tk < 0 ? 0 : (tk >= TT ? TT - 1 : tk);
    const unsigned short* src =
        (bufv ? Vp : Kp) + ((size_t)(b * TT + tkc)) * TC + h * TD + c * 8;
    uint4 v = *(const uint4*)src;
    unsigned short* dst = (bufv ? Vs : Ks) + r * ASTR + c * 8;
    uint2 lo; lo.x = v.x; lo.y = v.y;
    uint2 hi; hi.x = v.z; hi.y = v.w;
    *(uint2*)dst = lo; *(uint2*)(dst + 4) = hi;
  }
  if (tid < AROWS) {
    const int tk = t0 - WOVR + tid;
    mfs[tid] = (tk >= 0 && tk < TT) ? (mf[b * TT + tk] != 0.f ? 0.f : -1e4f)
                                    : -1e30f;
  }
  __syncthreads();

  const int t = t0 + tloc;
  const float qm = mf[b * TT + t];
  float q[16];
  {
    const unsigned short* qr = Qp + ((size_t)(b * TT + t)) * TC + h * TD + half * 16;
    #pragma unroll
    for (int c = 0; c < 2; c++) {
      u16x8 v = *(const u16x8*)(qr + c * 8);
      #pragma unroll
      for (int j = 0; j < 8; j++) q[c * 8 + j] = bf2f(v[j]);
    }
  }
  float e[TW];
  float smax = -3.0e38f;
  #pragma unroll
  for (int j = 0; j < TW; j++) {
    const unsigned short* kr = Ks + (tloc + j) * ASTR + half * 16;
    float acc = 0.f;
    #pragma unroll
    for (int c = 0; c < 4; c++) {
      uint2 w = *(const uint2*)(kr + c * 4);
      acc = fmaf(q[c*4+0], bf2f((unsigned short)(w.x & 0xffffu)), acc);
      acc = fmaf(q[c*4+1], bf2f((unsigned short)(w.x >> 16)), acc);
      acc = fmaf(q[c*4+2], bf2f((unsigned short)(w.y & 0xffffu)), acc);
      acc = fmaf(q[c*4+3], bf2f((unsigned short)(w.y >> 16)), acc);
    }
    acc += __shfl_xor(acc, 1, 64);
    const float sv = acc * SCALE + mfs[tloc + j];
    e[j] = sv;
    smax = fmaxf(smax, sv);
  }
  float den = 0.f;
  #pragma unroll
  for (int j = 0; j < TW; j++) { const float ev = __expf(e[j] - smax); e[j] = ev; den += ev; }
  float o[16] = {};
  #pragma unroll
  for (int j = 0; j < TW; j++) {
    const unsigned short* vr = Vs + (tloc + j) * ASTR + half * 16;
    const float p = e[j];
    #pragma unroll
    for (int c = 0; c < 4; c++) {
      uint2 w = *(const uint2*)(vr + c * 4);
      o[c*4+0] = fmaf(p, bf2f((unsigned short)(w.x & 0xffffu)), o[c*4+0]);
      o[c*4+1] = fmaf(p, bf2f((unsigned short)(w.x >> 16)), o[c*4+1]);
      o[c*4+2] = fmaf(p, bf2f((unsigned short)(w.y & 0xffffu)), o[c*4+2]);
      o[c*4+3] = fmaf(p, bf2f((unsigned short)(w.y >> 16)), o[c*4+3]);
    }
  }
  const float sc = qm / den;
  unsigned short tmp[16];
  #pragma unroll
  for (int i = 0; i < 16; i++) tmp[i] = f2bf(o[i] * sc);
  unsigned short* op = AO + ((size_t)(b * TT + t)) * TC + h * TD + half * 16;
  *(u16x8*)(op)     = *(const u16x8*)(tmp);
  *(u16x8*)(op + 8) = *(const u16x8*)(tmp + 8);
}

extern "C" void kernel_launch(void* const* d_in, const int* in_sizes, int n_in,
                              void* d_out, int out_size, void* d_ws, size_t ws_size,
                              hipStream_t stream) {
  const float* x       = (const float*)d_in[0];
  const float* w_qconv = (const float*)d_in[1];
  const float* w_kconv = (const float*)d_in[2];
  const float* w_vconv = (const float*)d_in[3];
  const float* g_q = (const float*)d_in[4];
  const float* b_q = (const float*)d_in[5];
  const float* g_k = (const float*)d_in[6];
  const float* b_k = (const float*)d_in[7];
  const float* g_v = (const float*)d_in[8];
  const float* b_v = (const float*)d_in[9];
  const float* w_query = (const float*)d_in[10];
  const float* b_query = (const float*)d_in[11];
  const float* w_key   = (const float*)d_in[12];
  const float* b_key   = (const float*)d_in[13];
  const float* w_value = (const float*)d_in[14];
  const float* b_value = (const float*)d_in[15];
  const float* w_proj  = (const float*)d_in[16];
  const float* b_proj  = (const float*)d_in[17];
  const unsigned char* mraw = (const unsigned char*)d_in[18];
  float* out = (float*)d_out;

  uint8_t* w8 = (uint8_t*)d_ws;
  float* mf            = (float*)w8;                                   // 36 KB
  unsigned short* Wbf  = (unsigned short*)(w8 + (1ull << 20));         // 2 MB
  unsigned short* Aall = (unsigned short*)(w8 + (4ull << 20));         // 28.3 MB
  unsigned short* QKV  = (unsigned short*)(w8 + (34ull << 20));        // 28.3 MB
  unsigned short* AO   = (unsigned short*)(w8 + (63ull << 20));        // 9.4 MB

  k_conv_ln_t<<<dim3(144, TB), dim3(512), 0, stream>>>(
      x, w_qconv, w_kconv, w_vconv, g_q, b_q, g_k, b_k, g_v, b_v,
      w_query, w_key, w_value, w_proj, mraw, Wbf, mf, out, Aall);
  k_gemm_mfma<0><<<dim3(864), dim3(256), 0, stream>>>(
      Aall, Wbf, b_query, b_key, b_value, QKV, nullptr, mf);
  k_attn_lds<<<dim3(TT / 128, TH, TB), dim3(256), 0, stream>>>(QKV, mf, AO);
  k_gemm_mfma<1><<<dim3(288), dim3(256), 0, stream>>>(
      AO, Wbf + 3 * TC * TC, b_proj, b_proj, b_proj, nullptr, out, mf);
}

// Round 15
// 90.631 us; speedup vs baseline: 1.6562x; 1.0724x over previous
//
#include <hip/hip_runtime.h>
#include <hip/hip_bf16.h>
#include <cstdint>
#include <cstddef>

#define TB 4
#define TC 512
#define TT 2304
#define TH 16
#define TD 32
#define TW 19
#define WOVR 9
#define EPSLN 1e-5f
#define SCALE 0.17677669529663687f   // 1/sqrt(32)
#define MTOT (TB * TT)               // 9216 rows
#define KSZ  512

typedef __attribute__((ext_vector_type(8))) short s16x8;
typedef __attribute__((ext_vector_type(8))) unsigned short u16x8;
typedef __attribute__((ext_vector_type(4))) float f32x4;

__device__ __forceinline__ float bf2f(unsigned short u) {
  union { unsigned int i; float f; } x; x.i = ((unsigned int)u) << 16; return x.f;
}
__device__ __forceinline__ unsigned short f2bf(float f) {
  union { __hip_bfloat16 h; unsigned short u; } c;
  c.h = __float2bfloat16(f);
  return c.u;
}
__device__ __forceinline__ void gload16(const void* g, void* l) {
  __builtin_amdgcn_global_load_lds(
      (const __attribute__((address_space(1))) unsigned int*)g,
      (__attribute__((address_space(3))) unsigned int*)l, 16, 0, 0);
}
__device__ __forceinline__ float mval(const unsigned char* mraw, int idx) {
  const uint32_t w0 = *(const uint32_t*)mraw;
  bool on;
  if (w0 == 1u)                 on = ((const int*)mraw)[idx] != 0;
  else if (w0 == 0x01010101u)   on = mraw[idx] != 0;
  else                          on = ((const float*)mraw)[idx] != 0.0f;
  return on ? 1.0f : 0.0f;
}

// ---- fused: prep (weights->bf16, mask->mf+tail) + 3x (conv3+mask+LN(C)) ----
// PROVEN R12 version (byte-identical). Lanes span t (coalesced 64B runs);
// conv weights + gamma/beta staged in LDS (padded); taps loaded directly.
__global__ __launch_bounds__(512) void k_conv_ln_t(
    const float* __restrict__ x,
    const float* __restrict__ wq, const float* __restrict__ wk, const float* __restrict__ wv,
    const float* __restrict__ gq, const float* __restrict__ bq,
    const float* __restrict__ gk, const float* __restrict__ bk,
    const float* __restrict__ gv, const float* __restrict__ bv,
    const float* __restrict__ wquery, const float* __restrict__ wkey,
    const float* __restrict__ wvalue, const float* __restrict__ wproj,
    const unsigned char* __restrict__ mraw,
    unsigned short* __restrict__ Wbf, float* __restrict__ mf,
    float* __restrict__ outtail, unsigned short* __restrict__ Aall) {
  const int b = blockIdx.y;
  const int t0 = blockIdx.x * 16;
  const int tid = threadIdx.x;
  const int tt = tid & 15, cg = tid >> 4;   // cg in [0,32), 16 channels each

  // ---- merged prep: weight pack + mask expand (grid-strided, 576x512) ----
  {
    const int gtid = (b * 144 + blockIdx.x) * 512 + tid;   // 294912 total
    #pragma unroll
    for (int rep = 0; rep < 4; rep++) {
      const int j = gtid + rep * 294912;
      if (j < 4 * TC * TC) {
        const int zz = j >> 18, r = j & (TC * TC - 1);
        const float* src = (zz == 0) ? wquery : (zz == 1) ? wkey
                          : (zz == 2) ? wvalue : wproj;
        Wbf[j] = f2bf(src[r]);
      }
    }
    if (gtid < TB * TT) {
      const float v = mval(mraw, gtid);
      mf[gtid] = v;
      outtail[(size_t)TB * TC * TT + gtid] = v;   // tuple output #2
    }
  }

  __shared__ float4 wlds[3][544];           // (w0,w1,w2,-) per channel, padded
  __shared__ float2 gblds[3][544];          // (gamma,beta) per channel, padded
  __shared__ float ps[3][32][17], ps2[3][32][17];
  __shared__ float mean_s[3][16], rstd_s[3][16];

  {
    const int c = tid, cp = c + (c >> 4);
    wlds[0][cp] = make_float4(wq[c*3], wq[c*3+1], wq[c*3+2], 0.f);
    wlds[1][cp] = make_float4(wk[c*3], wk[c*3+1], wk[c*3+2], 0.f);
    wlds[2][cp] = make_float4(wv[c*3], wv[c*3+1], wv[c*3+2], 0.f);
    gblds[0][cp] = make_float2(gq[c], bq[c]);
    gblds[1][cp] = make_float2(gk[c], bk[c]);
    gblds[2][cp] = make_float2(gv[c], bv[c]);
  }
  __syncthreads();

  const int tg = t0 + tt;
  const float m = mval(mraw, b * TT + tg);
  const int tm = tg > 0 ? tg - 1 : 0;
  const int tp = tg < TT - 1 ? tg + 1 : TT - 1;
  const float zl = (tg > 0) ? 1.f : 0.f;        // zero-pad left edge
  const float zr = (tg < TT - 1) ? 1.f : 0.f;   // zero-pad right edge

  const float* xb = x + ((size_t)(b * TC + cg * 16)) * TT;
  float xm[16], x0[16], xp[16];
  #pragma unroll
  for (int i = 0; i < 16; i++) {
    const float* xc = xb + (size_t)i * TT;
    xm[i] = xc[tm]; x0[i] = xc[tg]; xp[i] = xc[tp];
  }

  float s[3] = {}, s2[3] = {};
  unsigned int yp[3][8];
  #pragma unroll
  for (int i = 0; i < 16; i++) {
    const int cp = cg * 17 + i;
    const float xml = xm[i] * zl, xpl = xp[i] * zr;
    #pragma unroll
    for (int z = 0; z < 3; z++) {
      const float4 w = wlds[z][cp];
      const float y = (w.x * xml + w.y * x0[i] + w.z * xpl) * m;
      s[z] += y; s2[z] += y * y;
      const unsigned int h = f2bf(y);
      if ((i & 1) == 0) yp[z][i >> 1] = h;
      else              yp[z][i >> 1] |= h << 16;
    }
  }
  #pragma unroll
  for (int z = 0; z < 3; z++) {
    ps[z][cg][tt] = s[z]; ps2[z][cg][tt] = s2[z];
  }
  __syncthreads();
  if (tid < 48) {
    const int z = tid >> 4, tl = tid & 15;
    float su = 0.f, su2 = 0.f;
    #pragma unroll
    for (int g = 0; g < 32; g++) { su += ps[z][g][tl]; su2 += ps2[z][g][tl]; }
    const float mean = su * (1.f / TC);
    const float var  = su2 * (1.f / TC) - mean * mean;
    mean_s[z][tl] = mean;
    rstd_s[z][tl] = rsqrtf(fmaxf(var, 0.f) + EPSLN);
  }
  __syncthreads();

  #pragma unroll
  for (int z = 0; z < 3; z++) {
    const float mean = mean_s[z][tt], rs = rstd_s[z][tt];
    unsigned short tmp[16];
    #pragma unroll
    for (int i = 0; i < 16; i++) {
      const float2 gb = gblds[z][cg * 17 + i];
      const unsigned short hb = (unsigned short)(
          (i & 1) ? (yp[z][i >> 1] >> 16) : (yp[z][i >> 1] & 0xffffu));
      tmp[i] = f2bf((bf2f(hb) - mean) * rs * gb.x + gb.y);
    }
    unsigned short* oz = Aall + ((size_t)z * MTOT + b * TT + tg) * TC + cg * 16;
    *(u16x8*)(oz)     = *(const u16x8*)(tmp);
    *(u16x8*)(oz + 8) = *(const u16x8*)(tmp + 8);
  }
}

// ---------------- MFMA GEMM: D[m][n] = sum_k A[m][k] * W[n][k] (+bias[n]) ----
// PROVEN R12 schedule, templated on BM (block rows). BM=128: byte-identical
// to R12 (QKV). BM=64 (proj): same sync structure, A-staging 1 instr/thread,
// vmcnt constant = loads/thread/stage (3) by the same formula as the proven 4.
// 3-stage LDS pipeline, counted vmcnt; ONE combined "s_waitcnt vmcnt(N)
// lgkmcnt(0); s_barrier" per K-step. s_setprio around MFMA cluster.
// Operands swapped in mfma so D lane-dim = bt rows, reg-dim = channels.
template<int BM, int F32OUT>
__global__ __launch_bounds__(256) void k_gemm_mfma(
    const unsigned short* __restrict__ Abase, const unsigned short* __restrict__ Wbase,
    const float* __restrict__ bq, const float* __restrict__ bk, const float* __restrict__ bv,
    unsigned short* __restrict__ obf, float* __restrict__ of32,
    const float* __restrict__ mf) {
  constexpr int MI = BM / 32;            // acc tiles in m per wave
  constexpr int QA = BM / 64;            // A staging instrs per thread
  constexpr int NT = (MTOT / BM) * 4;    // tiles per z
  constexpr int ABUF = BM * 32;          // elements per A buffer
  const int nw = gridDim.x;              // multiple of 8
  int w = blockIdx.x;
  w = (w & 7) * (nw >> 3) + (w >> 3);    // chunked XCD swizzle
  const int z = w / NT;
  const int rem = w - z * NT;
  const int m0 = (rem >> 2) * BM;
  const int n0 = (rem & 3) * 128;

  const unsigned short* A = Abase + (size_t)z * MTOT * KSZ;
  const unsigned short* W = Wbase + (size_t)z * KSZ * KSZ;
  const float* bias = (z == 0) ? bq : (z == 1) ? bk : bv;

  // 3 A-buffers then 3 B-buffers (B always 128x32 = 4096 elem = 8KB)
  __shared__ __align__(16) unsigned short smem[3 * ABUF + 3 * 4096];
  const int tid = threadIdx.x;
  const int l = tid & 63, l15 = l & 15, l4 = l >> 4;
  const int wid = tid >> 6, wm = wid >> 1, wn = wid & 1;

  const int r0 = tid >> 2;
  const int c0 = (tid & 3) ^ ((r0 >> 1) & 3);
  const int r1 = r0 + 64;
  const int c1 = (tid & 3) ^ ((r1 >> 1) & 3);
  const size_t gaA0 = (size_t)(m0 + r0) * KSZ + c0 * 8;
  const size_t gaA1 = (size_t)(m0 + (QA == 2 ? r1 : r0)) * KSZ +
                      (QA == 2 ? c1 : c0) * 8;      // unused when QA==1
  const size_t gaB0 = (size_t)(n0 + r0) * KSZ + c0 * 8;
  const size_t gaB1 = (size_t)(n0 + r1) * KSZ + c1 * 8;

  int offA[MI], offB[4];
  #pragma unroll
  for (int i = 0; i < MI; i++) {
    const int ra = wm * (BM / 2) + i * 16 + l15;
    offA[i] = (ra * 4 + (l4 ^ ((ra >> 1) & 3))) * 8;
  }
  #pragma unroll
  for (int j = 0; j < 4; j++) {
    const int rb = wn * 64 + j * 16 + l15;
    offB[j] = (rb * 4 + (l4 ^ ((rb >> 1) & 3))) * 8;
  }

  #define STAGE(buf, kk)                                           \
    do {                                                           \
      unsigned short* Ad = smem + (buf) * ABUF;                    \
      unsigned short* Bd = smem + 3 * ABUF + (buf) * 4096;         \
      gload16(A + gaA0 + (kk), Ad + tid * 8);                      \
      if (QA == 2) gload16(A + gaA1 + (kk), Ad + (tid + 256) * 8); \
      gload16(W + gaB0 + (kk), Bd + tid * 8);                      \
      gload16(W + gaB1 + (kk), Bd + (tid + 256) * 8);              \
    } while (0)

  f32x4 acc[MI][4] = {};
  STAGE(0, 0);
  STAGE(1, 32);
  // tile0 landed (my oldest stage of 2 outstanding), all threads synced
  if (QA == 2) asm volatile("s_waitcnt vmcnt(4)\ns_barrier" ::: "memory");
  else         asm volatile("s_waitcnt vmcnt(3)\ns_barrier" ::: "memory");

  #pragma unroll
  for (int t = 0; t < 16; ++t) {
    if (t + 2 < 16) STAGE((t + 2) % 3, (t + 2) * 32);
    const unsigned short* Ac = smem + (t % 3) * ABUF;
    const unsigned short* Bc = smem + 3 * ABUF + (t % 3) * 4096;
    s16x8 av[MI], bw[4];
    #pragma unroll
    for (int i = 0; i < MI; i++) av[i] = *(const s16x8*)(Ac + offA[i]);
    #pragma unroll
    for (int j = 0; j < 4; j++)  bw[j] = *(const s16x8*)(Bc + offB[j]);
    __builtin_amdgcn_s_setprio(1);
    #pragma unroll
    for (int mi = 0; mi < MI; mi++)
      #pragma unroll
      for (int nj = 0; nj < 4; nj++)
        acc[mi][nj] = __builtin_amdgcn_mfma_f32_16x16x32_bf16(
            bw[nj], av[mi], acc[mi][nj], 0, 0, 0);   // swapped: D reg-dim = ch
    __builtin_amdgcn_s_setprio(0);
    // lgkmcnt(0): my ds_reads done (no overwrite race); vmcnt(N): tile t+1
    // landed (t+2's loads still in flight); s_barrier: all threads agree.
    if (t < 14) {
      if (QA == 2)
        asm volatile("s_waitcnt vmcnt(4) lgkmcnt(0)\ns_barrier" ::: "memory");
      else
        asm volatile("s_waitcnt vmcnt(3) lgkmcnt(0)\ns_barrier" ::: "memory");
    } else if (t == 14) {
      asm volatile("s_waitcnt vmcnt(0) lgkmcnt(0)\ns_barrier" ::: "memory");
    }
  }
  #undef STAGE

  if (!F32OUT) {
    // bf16 out [bt][512]: lane holds 4 consecutive channels -> 8B packed store
    unsigned short* O = obf + (size_t)z * MTOT * KSZ;
    #pragma unroll
    for (int nj = 0; nj < 4; nj++) {
      const int ch0 = n0 + wn * 64 + nj * 16 + l4 * 4;
      const float4 bi = *(const float4*)&bias[ch0];
      #pragma unroll
      for (int mi = 0; mi < MI; mi++) {
        const int bt = m0 + wm * (BM / 2) + mi * 16 + l15;
        uint2 pk;
        pk.x = (uint32_t)f2bf(acc[mi][nj][0] + bi.x) |
               ((uint32_t)f2bf(acc[mi][nj][1] + bi.y) << 16);
        pk.y = (uint32_t)f2bf(acc[mi][nj][2] + bi.z) |
               ((uint32_t)f2bf(acc[mi][nj][3] + bi.w) << 16);
        *(uint2*)&O[(size_t)bt * KSZ + ch0] = pk;
      }
    }
  } else {
    // f32 out [B][C][T] with fused mask; lanes span 16 consecutive t
    const int bb = m0 / TT;
    const int tl0 = m0 - bb * TT;
    #pragma unroll
    for (int mi = 0; mi < MI; mi++) {
      const int bt = m0 + wm * (BM / 2) + mi * 16 + l15;
      const int tloc = tl0 + wm * (BM / 2) + mi * 16 + l15;
      const float mm = mf[bt];
      #pragma unroll
      for (int nj = 0; nj < 4; nj++) {
        const int ch0 = n0 + wn * 64 + nj * 16 + l4 * 4;
        const float4 bi = *(const float4*)&bias[ch0];
        #pragma unroll
        for (int r = 0; r < 4; r++) {
          const float biv = r == 0 ? bi.x : r == 1 ? bi.y : r == 2 ? bi.z : bi.w;
          of32[((size_t)(bb * TC + ch0 + r)) * TT + tloc] =
              (acc[mi][nj][r] + biv) * mm;
        }
      }
    }
  }
}

// ---------------- banded attention, LDS-staged K/V, d-split x2 ----------------
#define AROWS (128 + 2 * WOVR)   // 146
#define ASTR  36                 // 32 data + 4 pad ushorts = 72B rows
__global__ __launch_bounds__(256) void k_attn_lds(
    const unsigned short* __restrict__ QKV, const float* __restrict__ mf,
    unsigned short* __restrict__ AO) {
  const int t0 = blockIdx.x * 128;
  const int h = blockIdx.y, b = blockIdx.z;
  const int tid = threadIdx.x;
  const int tloc = tid >> 1, half = tid & 1;
  const size_t SZ = (size_t)MTOT * KSZ;
  const unsigned short* Qp = QKV;
  const unsigned short* Kp = QKV + SZ;
  const unsigned short* Vp = QKV + 2 * SZ;
  __shared__ unsigned short Ks[AROWS * ASTR], Vs[AROWS * ASTR];
  __shared__ float mfs[AROWS];

  for (int idx = tid; idx < 2 * AROWS * 4; idx += 256) {
    const int bufv = idx >= AROWS * 4;
    const int ci = idx - bufv * AROWS * 4;
    const int r = ci >> 2, c = ci & 3;
    const int tk = t0 - WOVR + r;
    const int tkc = tk < 0 ? 0 : (tk >= TT ? TT - 1 : tk);
    const unsigned short* src =
        (bufv ? Vp : Kp) + ((size_t)(b * TT + tkc)) * TC + h * TD + c * 8;
    uint4 v = *(const uint4*)src;
    unsigned short* dst = (bufv ? Vs : Ks) + r * ASTR + c * 8;
    uint2 lo; lo.x = v.x; lo.y = v.y;
    uint2 hi; hi.x = v.z; hi.y = v.w;
    *(uint2*)dst = lo; *(uint2*)(dst + 4) = hi;
  }
  if (tid < AROWS) {
    const int tk = t0 - WOVR + tid;
    mfs[tid] = (tk >= 0 && tk < TT) ? (mf[b * TT + tk] != 0.f ? 0.f : -1e4f)
                                    : -1e30f;
  }
  __syncthreads();

  const int t = t0 + tloc;
  const float qm = mf[b * TT + t];
  float q[16];
  {
    const unsigned short* qr = Qp + ((size_t)(b * TT + t)) * TC + h * TD + half * 16;
    #pragma unroll
    for (int c = 0; c < 2; c++) {
      u16x8 v = *(const u16x8*)(qr + c * 8);
      #pragma unroll
      for (int j = 0; j < 8; j++) q[c * 8 + j] = bf2f(v[j]);
    }
  }
  float e[TW];
  float smax = -3.0e38f;
  #pragma unroll
  for (int j = 0; j < TW; j++) {
    const unsigned short* kr = Ks + (tloc + j) * ASTR + half * 16;
    float acc = 0.f;
    #pragma unroll
    for (int c = 0; c < 4; c++) {
      uint2 w = *(const uint2*)(kr + c * 4);
      acc = fmaf(q[c*4+0], bf2f((unsigned short)(w.x & 0xffffu)), acc);
      acc = fmaf(q[c*4+1], bf2f((unsigned short)(w.x >> 16)), acc);
      acc = fmaf(q[c*4+2], bf2f((unsigned short)(w.y & 0xffffu)), acc);
      acc = fmaf(q[c*4+3], bf2f((unsigned short)(w.y >> 16)), acc);
    }
    acc += __shfl_xor(acc, 1, 64);
    const float sv = acc * SCALE + mfs[tloc + j];
    e[j] = sv;
    smax = fmaxf(smax, sv);
  }
  float den = 0.f;
  #pragma unroll
  for (int j = 0; j < TW; j++) { const float ev = __expf(e[j] - smax); e[j] = ev; den += ev; }
  float o[16] = {};
  #pragma unroll
  for (int j = 0; j < TW; j++) {
    const unsigned short* vr = Vs + (tloc + j) * ASTR + half * 16;
    const float p = e[j];
    #pragma unroll
    for (int c = 0; c < 4; c++) {
      uint2 w = *(const uint2*)(vr + c * 4);
      o[c*4+0] = fmaf(p, bf2f((unsigned short)(w.x & 0xffffu)), o[c*4+0]);
      o[c*4+1] = fmaf(p, bf2f((unsigned short)(w.x >> 16)), o[c*4+1]);
      o[c*4+2] = fmaf(p, bf2f((unsigned short)(w.y & 0xffffu)), o[c*4+2]);
      o[c*4+3] = fmaf(p, bf2f((unsigned short)(w.y >> 16)), o[c*4+3]);
    }
  }
  const float sc = qm / den;
  unsigned short tmp[16];
  #pragma unroll
  for (int i = 0; i < 16; i++) tmp[i] = f2bf(o[i] * sc);
  unsigned short* op = AO + ((size_t)(b * TT + t)) * TC + h * TD + half * 16;
  *(u16x8*)(op)     = *(const u16x8*)(tmp);
  *(u16x8*)(op + 8) = *(const u16x8*)(tmp + 8);
}

extern "C" void kernel_launch(void* const* d_in, const int* in_sizes, int n_in,
                              void* d_out, int out_size, void* d_ws, size_t ws_size,
                              hipStream_t stream) {
  const float* x       = (const float*)d_in[0];
  const float* w_qconv = (const float*)d_in[1];
  const float* w_kconv = (const float*)d_in[2];
  const float* w_vconv = (const float*)d_in[3];
  const float* g_q = (const float*)d_in[4];
  const float* b_q = (const float*)d_in[5];
  const float* g_k = (const float*)d_in[6];
  const float* b_k = (const float*)d_in[7];
  const float* g_v = (const float*)d_in[8];
  const float* b_v = (const float*)d_in[9];
  const float* w_query = (const float*)d_in[10];
  const float* b_query = (const float*)d_in[11];
  const float* w_key   = (const float*)d_in[12];
  const float* b_key   = (const float*)d_in[13];
  const float* w_value = (const float*)d_in[14];
  const float* b_value = (const float*)d_in[15];
  const float* w_proj  = (const float*)d_in[16];
  const float* b_proj  = (const float*)d_in[17];
  const unsigned char* mraw = (const unsigned char*)d_in[18];
  float* out = (float*)d_out;

  uint8_t* w8 = (uint8_t*)d_ws;
  float* mf            = (float*)w8;                                   // 36 KB
  unsigned short* Wbf  = (unsigned short*)(w8 + (1ull << 20));         // 2 MB
  unsigned short* Aall = (unsigned short*)(w8 + (4ull << 20));         // 28.3 MB
  unsigned short* QKV  = (unsigned short*)(w8 + (34ull << 20));        // 28.3 MB
  unsigned short* AO   = (unsigned short*)(w8 + (63ull << 20));        // 9.4 MB

  k_conv_ln_t<<<dim3(144, TB), dim3(512), 0, stream>>>(
      x, w_qconv, w_kconv, w_vconv, g_q, b_q, g_k, b_k, g_v, b_v,
      w_query, w_key, w_value, w_proj, mraw, Wbf, mf, out, Aall);
  k_gemm_mfma<128, 0><<<dim3(864), dim3(256), 0, stream>>>(
      Aall, Wbf, b_query, b_key, b_value, QKV, nullptr, mf);
  k_attn_lds<<<dim3(TT / 128, TH, TB), dim3(256), 0, stream>>>(QKV, mf, AO);
  k_gemm_mfma<64, 1><<<dim3(576), dim3(256), 0, stream>>>(
      AO, Wbf + 3 * TC * TC, b_proj, b_proj, b_proj, nullptr, out, mf);
}

// Round 16
// 89.904 us; speedup vs baseline: 1.6697x; 1.0081x over previous
//
#include <hip/hip_runtime.h>
#include <hip/hip_bf16.h>
#include <cstdint>
#include <cstddef>

#define TB 4
#define TC 512
#define TT 2304
#define TH 16
#define TD 32
#define TW 19
#define WOVR 9
#define EPSLN 1e-5f
#define SCALE 0.17677669529663687f   // 1/sqrt(32)
#define MTOT (TB * TT)               // 9216 rows
#define KSZ  512

typedef __attribute__((ext_vector_type(8))) short s16x8;
typedef __attribute__((ext_vector_type(8))) unsigned short u16x8;
typedef __attribute__((ext_vector_type(4))) float f32x4;

__device__ __forceinline__ float bf2f(unsigned short u) {
  union { unsigned int i; float f; } x; x.i = ((unsigned int)u) << 16; return x.f;
}
__device__ __forceinline__ unsigned short f2bf(float f) {
  union { __hip_bfloat16 h; unsigned short u; } c;
  c.h = __float2bfloat16(f);
  return c.u;
}
__device__ __forceinline__ void gload16(const void* g, void* l) {
  __builtin_amdgcn_global_load_lds(
      (const __attribute__((address_space(1))) unsigned int*)g,
      (__attribute__((address_space(3))) unsigned int*)l, 16, 0, 0);
}
__device__ __forceinline__ float mval(const unsigned char* mraw, int idx) {
  const uint32_t w0 = *(const uint32_t*)mraw;
  bool on;
  if (w0 == 1u)                 on = ((const int*)mraw)[idx] != 0;
  else if (w0 == 0x01010101u)   on = mraw[idx] != 0;
  else                          on = ((const float*)mraw)[idx] != 0.0f;
  return on ? 1.0f : 0.0f;
}

// ---- fused: prep (weights->bf16, mask->mf+tail) + 3x (conv3+mask+LN(C)) ----
// PROVEN R12 version (byte-identical). Lanes span t (coalesced 64B runs);
// conv weights + gamma/beta staged in LDS (padded); taps loaded directly.
__global__ __launch_bounds__(512) void k_conv_ln_t(
    const float* __restrict__ x,
    const float* __restrict__ wq, const float* __restrict__ wk, const float* __restrict__ wv,
    const float* __restrict__ gq, const float* __restrict__ bq,
    const float* __restrict__ gk, const float* __restrict__ bk,
    const float* __restrict__ gv, const float* __restrict__ bv,
    const float* __restrict__ wquery, const float* __restrict__ wkey,
    const float* __restrict__ wvalue, const float* __restrict__ wproj,
    const unsigned char* __restrict__ mraw,
    unsigned short* __restrict__ Wbf, float* __restrict__ mf,
    float* __restrict__ outtail, unsigned short* __restrict__ Aall) {
  const int b = blockIdx.y;
  const int t0 = blockIdx.x * 16;
  const int tid = threadIdx.x;
  const int tt = tid & 15, cg = tid >> 4;   // cg in [0,32), 16 channels each

  // ---- merged prep: weight pack + mask expand (grid-strided, 576x512) ----
  {
    const int gtid = (b * 144 + blockIdx.x) * 512 + tid;   // 294912 total
    #pragma unroll
    for (int rep = 0; rep < 4; rep++) {
      const int j = gtid + rep * 294912;
      if (j < 4 * TC * TC) {
        const int zz = j >> 18, r = j & (TC * TC - 1);
        const float* src = (zz == 0) ? wquery : (zz == 1) ? wkey
                          : (zz == 2) ? wvalue : wproj;
        Wbf[j] = f2bf(src[r]);
      }
    }
    if (gtid < TB * TT) {
      const float v = mval(mraw, gtid);
      mf[gtid] = v;
      outtail[(size_t)TB * TC * TT + gtid] = v;   // tuple output #2
    }
  }

  __shared__ float4 wlds[3][544];           // (w0,w1,w2,-) per channel, padded
  __shared__ float2 gblds[3][544];          // (gamma,beta) per channel, padded
  __shared__ float ps[3][32][17], ps2[3][32][17];
  __shared__ float mean_s[3][16], rstd_s[3][16];

  {
    const int c = tid, cp = c + (c >> 4);
    wlds[0][cp] = make_float4(wq[c*3], wq[c*3+1], wq[c*3+2], 0.f);
    wlds[1][cp] = make_float4(wk[c*3], wk[c*3+1], wk[c*3+2], 0.f);
    wlds[2][cp] = make_float4(wv[c*3], wv[c*3+1], wv[c*3+2], 0.f);
    gblds[0][cp] = make_float2(gq[c], bq[c]);
    gblds[1][cp] = make_float2(gk[c], bk[c]);
    gblds[2][cp] = make_float2(gv[c], bv[c]);
  }
  __syncthreads();

  const int tg = t0 + tt;
  const float m = mval(mraw, b * TT + tg);
  const int tm = tg > 0 ? tg - 1 : 0;
  const int tp = tg < TT - 1 ? tg + 1 : TT - 1;
  const float zl = (tg > 0) ? 1.f : 0.f;        // zero-pad left edge
  const float zr = (tg < TT - 1) ? 1.f : 0.f;   // zero-pad right edge

  const float* xb = x + ((size_t)(b * TC + cg * 16)) * TT;
  float xm[16], x0[16], xp[16];
  #pragma unroll
  for (int i = 0; i < 16; i++) {
    const float* xc = xb + (size_t)i * TT;
    xm[i] = xc[tm]; x0[i] = xc[tg]; xp[i] = xc[tp];
  }

  float s[3] = {}, s2[3] = {};
  unsigned int yp[3][8];
  #pragma unroll
  for (int i = 0; i < 16; i++) {
    const int cp = cg * 17 + i;
    const float xml = xm[i] * zl, xpl = xp[i] * zr;
    #pragma unroll
    for (int z = 0; z < 3; z++) {
      const float4 w = wlds[z][cp];
      const float y = (w.x * xml + w.y * x0[i] + w.z * xpl) * m;
      s[z] += y; s2[z] += y * y;
      const unsigned int h = f2bf(y);
      if ((i & 1) == 0) yp[z][i >> 1] = h;
      else              yp[z][i >> 1] |= h << 16;
    }
  }
  #pragma unroll
  for (int z = 0; z < 3; z++) {
    ps[z][cg][tt] = s[z]; ps2[z][cg][tt] = s2[z];
  }
  __syncthreads();
  if (tid < 48) {
    const int z = tid >> 4, tl = tid & 15;
    float su = 0.f, su2 = 0.f;
    #pragma unroll
    for (int g = 0; g < 32; g++) { su += ps[z][g][tl]; su2 += ps2[z][g][tl]; }
    const float mean = su * (1.f / TC);
    const float var  = su2 * (1.f / TC) - mean * mean;
    mean_s[z][tl] = mean;
    rstd_s[z][tl] = rsqrtf(fmaxf(var, 0.f) + EPSLN);
  }
  __syncthreads();

  #pragma unroll
  for (int z = 0; z < 3; z++) {
    const float mean = mean_s[z][tt], rs = rstd_s[z][tt];
    unsigned short tmp[16];
    #pragma unroll
    for (int i = 0; i < 16; i++) {
      const float2 gb = gblds[z][cg * 17 + i];
      const unsigned short hb = (unsigned short)(
          (i & 1) ? (yp[z][i >> 1] >> 16) : (yp[z][i >> 1] & 0xffffu));
      tmp[i] = f2bf((bf2f(hb) - mean) * rs * gb.x + gb.y);
    }
    unsigned short* oz = Aall + ((size_t)z * MTOT + b * TT + tg) * TC + cg * 16;
    *(u16x8*)(oz)     = *(const u16x8*)(tmp);
    *(u16x8*)(oz + 8) = *(const u16x8*)(tmp + 8);
  }
}

// ---------------- MFMA GEMM: D[m][n] = sum_k A[m][k] * W[n][k] (+bias[n]) ----
// PROVEN R12 schedule (byte-identical): 128x128 tile, 4 waves (2x2), 3-stage
// LDS pipeline, counted vmcnt; ONE combined "s_waitcnt vmcnt(N) lgkmcnt(0);
// s_barrier" per K-step. s_setprio around MFMA cluster. Operands swapped in
// mfma so D lane-dim = bt rows, reg-dim = channels.
template<int F32OUT>
__global__ __launch_bounds__(256) void k_gemm_mfma(
    const unsigned short* __restrict__ Abase, const unsigned short* __restrict__ Wbase,
    const float* __restrict__ bq, const float* __restrict__ bk, const float* __restrict__ bv,
    unsigned short* __restrict__ obf, float* __restrict__ of32,
    const float* __restrict__ mf) {
  const int nw = gridDim.x;                       // multiple of 8
  int w = blockIdx.x;
  w = (w & 7) * (nw >> 3) + (w >> 3);             // chunked XCD swizzle
  const int z = w / 288;                          // 288 = 72 m-tiles * 4 n-tiles
  const int rem = w - z * 288;
  const int m0 = (rem >> 2) * 128;
  const int n0 = (rem & 3) * 128;

  const unsigned short* A = Abase + (size_t)z * MTOT * KSZ;
  const unsigned short* W = Wbase + (size_t)z * KSZ * KSZ;
  const float* bias = (z == 0) ? bq : (z == 1) ? bk : bv;

  // 3 A-buffers then 3 B-buffers, each 128x32 bf16 = 8KB; total 48KB
  __shared__ __align__(16) unsigned short smem[6 * 4096];
  const int tid = threadIdx.x;
  const int l = tid & 63, l15 = l & 15, l4 = l >> 4;
  const int wid = tid >> 6, wm = wid >> 1, wn = wid & 1;

  const int r0 = tid >> 2;
  const int c0 = (tid & 3) ^ ((r0 >> 1) & 3);
  const int r1 = r0 + 64;
  const int c1 = (tid & 3) ^ ((r1 >> 1) & 3);
  const size_t gaA0 = (size_t)(m0 + r0) * KSZ + c0 * 8;
  const size_t gaA1 = (size_t)(m0 + r1) * KSZ + c1 * 8;
  const size_t gaB0 = (size_t)(n0 + r0) * KSZ + c0 * 8;
  const size_t gaB1 = (size_t)(n0 + r1) * KSZ + c1 * 8;

  int offA[4], offB[4];
  #pragma unroll
  for (int i = 0; i < 4; i++) {
    const int ra = wm * 64 + i * 16 + l15;
    offA[i] = (ra * 4 + (l4 ^ ((ra >> 1) & 3))) * 8;
    const int rb = wn * 64 + i * 16 + l15;
    offB[i] = (rb * 4 + (l4 ^ ((rb >> 1) & 3))) * 8;
  }

  #define STAGE(buf, kk)                                           \
    do {                                                           \
      unsigned short* Ad = smem + (buf) * 4096;                    \
      unsigned short* Bd = smem + 3 * 4096 + (buf) * 4096;         \
      gload16(A + gaA0 + (kk), Ad + tid * 8);                      \
      gload16(A + gaA1 + (kk), Ad + (tid + 256) * 8);              \
      gload16(W + gaB0 + (kk), Bd + tid * 8);                      \
      gload16(W + gaB1 + (kk), Bd + (tid + 256) * 8);              \
    } while (0)

  f32x4 acc[4][4] = {};
  STAGE(0, 0);
  STAGE(1, 32);
  // tile0 landed (my 4 oldest of 8 outstanding), all threads synced
  asm volatile("s_waitcnt vmcnt(4)\ns_barrier" ::: "memory");

  #pragma unroll
  for (int t = 0; t < 16; ++t) {
    if (t + 2 < 16) STAGE((t + 2) % 3, (t + 2) * 32);
    const unsigned short* Ac = smem + (t % 3) * 4096;
    const unsigned short* Bc = smem + 3 * 4096 + (t % 3) * 4096;
    s16x8 av[4], bw[4];
    #pragma unroll
    for (int i = 0; i < 4; i++) {
      av[i] = *(const s16x8*)(Ac + offA[i]);
      bw[i] = *(const s16x8*)(Bc + offB[i]);
    }
    __builtin_amdgcn_s_setprio(1);
    #pragma unroll
    for (int mi = 0; mi < 4; mi++)
      #pragma unroll
      for (int nj = 0; nj < 4; nj++)
        acc[mi][nj] = __builtin_amdgcn_mfma_f32_16x16x32_bf16(
            bw[nj], av[mi], acc[mi][nj], 0, 0, 0);   // swapped: D reg-dim = ch
    __builtin_amdgcn_s_setprio(0);
    // lgkmcnt(0): my ds_reads done (no overwrite race); vmcnt(4): tile t+1
    // landed (4 loads for t+2 still in flight); s_barrier: all threads agree.
    if (t < 14)
      asm volatile("s_waitcnt vmcnt(4) lgkmcnt(0)\ns_barrier" ::: "memory");
    else if (t == 14)
      asm volatile("s_waitcnt vmcnt(0) lgkmcnt(0)\ns_barrier" ::: "memory");
  }
  #undef STAGE

  if (!F32OUT) {
    // bf16 out [bt][512]: lane holds 4 consecutive channels -> 8B packed store
    unsigned short* O = obf + (size_t)z * MTOT * KSZ;
    #pragma unroll
    for (int nj = 0; nj < 4; nj++) {
      const int ch0 = n0 + wn * 64 + nj * 16 + l4 * 4;
      const float4 bi = *(const float4*)&bias[ch0];
      #pragma unroll
      for (int mi = 0; mi < 4; mi++) {
        const int bt = m0 + wm * 64 + mi * 16 + l15;
        uint2 pk;
        pk.x = (uint32_t)f2bf(acc[mi][nj][0] + bi.x) |
               ((uint32_t)f2bf(acc[mi][nj][1] + bi.y) << 16);
        pk.y = (uint32_t)f2bf(acc[mi][nj][2] + bi.z) |
               ((uint32_t)f2bf(acc[mi][nj][3] + bi.w) << 16);
        *(uint2*)&O[(size_t)bt * KSZ + ch0] = pk;
      }
    }
  } else {
    // f32 out [B][C][T] with fused mask; lanes span 16 consecutive t
    const int bb = m0 / TT;
    const int tl0 = m0 - bb * TT;
    #pragma unroll
    for (int mi = 0; mi < 4; mi++) {
      const int bt = m0 + wm * 64 + mi * 16 + l15;
      const int tloc = tl0 + wm * 64 + mi * 16 + l15;
      const float mm = mf[bt];
      #pragma unroll
      for (int nj = 0; nj < 4; nj++) {
        const int ch0 = n0 + wn * 64 + nj * 16 + l4 * 4;
        const float4 bi = *(const float4*)&bias[ch0];
        #pragma unroll
        for (int r = 0; r < 4; r++) {
          const float biv = r == 0 ? bi.x : r == 1 ? bi.y : r == 2 ? bi.z : bi.w;
          of32[((size_t)(bb * TC + ch0 + r)) * TT + tloc] =
              (acc[mi][nj][r] + biv) * mm;
        }
      }
    }
  }
}

// ---------------- banded attention, LDS-staged K/V, d-split x2 ----------------
#define AROWS (128 + 2 * WOVR)   // 146
#define ASTR  36                 // 32 data + 4 pad ushorts = 72B rows
__global__ __launch_bounds__(256) void k_attn_lds(
    const unsigned short* __restrict__ QKV, const float* __restrict__ mf,
    unsigned short* __restrict__ AO) {
  const int t0 = blockIdx.x * 128;
  const int h = blockIdx.y, b = blockIdx.z;
  const int tid = threadIdx.x;
  const int tloc = tid >> 1, half = tid & 1;
  const size_t SZ = (size_t)MTOT * KSZ;
  const unsigned short* Qp = QKV;
  const unsigned short* Kp = QKV + SZ;
  const unsigned short* Vp = QKV + 2 * SZ;
  __shared__ unsigned short Ks[AROWS * ASTR], Vs[AROWS * ASTR];
  __shared__ float mfs[AROWS];

  for (int idx = tid; idx < 2 * AROWS * 4; idx += 256) {
    const int bufv = idx >= AROWS * 4;
    const int ci = idx - bufv * AROWS * 4;
    const int r = ci >> 2, c = ci & 3;
    const int tk = t0 - WOVR + r;
    const int tkc = tk < 0 ? 0 : (tk >= TT ? TT - 1 : tk);
    const unsigned short* src =
        (bufv ? Vp : Kp) + ((size_t)(b * TT + tkc)) * TC + h * TD + c * 8;
    uint4 v = *(const uint4*)src;
    unsigned short* dst = (bufv ? Vs : Ks) + r * ASTR + c * 8;
    uint2 lo; lo.x = v.x; lo.y = v.y;
    uint2 hi; hi.x = v.z; hi.y = v.w;
    *(uint2*)dst = lo; *(uint2*)(dst + 4) = hi;
  }
  if (tid < AROWS) {
    const int tk = t0 - WOVR + tid;
    mfs[tid] = (tk >= 0 && tk < TT) ? (mf[b * TT + tk] != 0.f ? 0.f : -1e4f)
                                    : -1e30f;
  }
  __syncthreads();

  const int t = t0 + tloc;
  const float qm = mf[b * TT + t];
  float q[16];
  {
    const unsigned short* qr = Qp + ((size_t)(b * TT + t)) * TC + h * TD + half * 16;
    #pragma unroll
    for (int c = 0; c < 2; c++) {
      u16x8 v = *(const u16x8*)(qr + c * 8);
      #pragma unroll
      for (int j = 0; j < 8; j++) q[c * 8 + j] = bf2f(v[j]);
    }
  }
  float e[TW];
  float smax = -3.0e38f;
  #pragma unroll
  for (int j = 0; j < TW; j++) {
    const unsigned short* kr = Ks + (tloc + j) * ASTR + half * 16;
    float acc = 0.f;
    #pragma unroll
    for (int c = 0; c < 4; c++) {
      uint2 w = *(const uint2*)(kr + c * 4);
      acc = fmaf(q[c*4+0], bf2f((unsigned short)(w.x & 0xffffu)), acc);
      acc = fmaf(q[c*4+1], bf2f((unsigned short)(w.x >> 16)), acc);
      acc = fmaf(q[c*4+2], bf2f((unsigned short)(w.y & 0xffffu)), acc);
      acc = fmaf(q[c*4+3], bf2f((unsigned short)(w.y >> 16)), acc);
    }
    acc += __shfl_xor(acc, 1, 64);
    const float sv = acc * SCALE + mfs[tloc + j];
    e[j] = sv;
    smax = fmaxf(smax, sv);
  }
  float den = 0.f;
  #pragma unroll
  for (int j = 0; j < TW; j++) { const float ev = __expf(e[j] - smax); e[j] = ev; den += ev; }
  float o[16] = {};
  #pragma unroll
  for (int j = 0; j < TW; j++) {
    const unsigned short* vr = Vs + (tloc + j) * ASTR + half * 16;
    const float p = e[j];
    #pragma unroll
    for (int c = 0; c < 4; c++) {
      uint2 w = *(const uint2*)(vr + c * 4);
      o[c*4+0] = fmaf(p, bf2f((unsigned short)(w.x & 0xffffu)), o[c*4+0]);
      o[c*4+1] = fmaf(p, bf2f((unsigned short)(w.x >> 16)), o[c*4+1]);
      o[c*4+2] = fmaf(p, bf2f((unsigned short)(w.y & 0xffffu)), o[c*4+2]);
      o[c*4+3] = fmaf(p, bf2f((unsigned short)(w.y >> 16)), o[c*4+3]);
    }
  }
  const float sc = qm / den;
  unsigned short tmp[16];
  #pragma unroll
  for (int i = 0; i < 16; i++) tmp[i] = f2bf(o[i] * sc);
  unsigned short* op = AO + ((size_t)(b * TT + t)) * TC + h * TD + half * 16;
  *(u16x8*)(op)     = *(const u16x8*)(tmp);
  *(u16x8*)(op + 8) = *(const u16x8*)(tmp + 8);
}

extern "C" void kernel_launch(void* const* d_in, const int* in_sizes, int n_in,
                              void* d_out, int out_size, void* d_ws, size_t ws_size,
                              hipStream_t stream) {
  const float* x       = (const float*)d_in[0];
  const float* w_qconv = (const float*)d_in[1];
  const float* w_kconv = (const float*)d_in[2];
  const float* w_vconv = (const float*)d_in[3];
  const float* g_q = (const float*)d_in[4];
  const float* b_q = (const float*)d_in[5];
  const float* g_k = (const float*)d_in[6];
  const float* b_k = (const float*)d_in[7];
  const float* g_v = (const float*)d_in[8];
  const float* b_v = (const float*)d_in[9];
  const float* w_query = (const float*)d_in[10];
  const float* b_query = (const float*)d_in[11];
  const float* w_key   = (const float*)d_in[12];
  const float* b_key   = (const float*)d_in[13];
  const float* w_value = (const float*)d_in[14];
  const float* b_value = (const float*)d_in[15];
  const float* w_proj  = (const float*)d_in[16];
  const float* b_proj  = (const float*)d_in[17];
  const unsigned char* mraw = (const unsigned char*)d_in[18];
  float* out = (float*)d_out;

  uint8_t* w8 = (uint8_t*)d_ws;
  float* mf            = (float*)w8;                                   // 36 KB
  unsigned short* Wbf  = (unsigned short*)(w8 + (1ull << 20));         // 2 MB
  unsigned short* Aall = (unsigned short*)(w8 + (4ull << 20));         // 28.3 MB
  unsigned short* QKV  = (unsigned short*)(w8 + (34ull << 20));        // 28.3 MB
  unsigned short* AO   = (unsigned short*)(w8 + (63ull << 20));        // 9.4 MB

  k_conv_ln_t<<<dim3(144, TB), dim3(512), 0, stream>>>(
      x, w_qconv, w_kconv, w_vconv, g_q, b_q, g_k, b_k, g_v, b_v,
      w_query, w_key, w_value, w_proj, mraw, Wbf, mf, out, Aall);
  k_gemm_mfma<0><<<dim3(864), dim3(256), 0, stream>>>(
      Aall, Wbf, b_query, b_key, b_value, QKV, nullptr, mf);
  k_attn_lds<<<dim3(TT / 128, TH, TB), dim3(256), 0, stream>>>(QKV, mf, AO);
  k_gemm_mfma<1><<<dim3(288), dim3(256), 0, stream>>>(
      AO, Wbf + 3 * TC * TC, b_proj, b_proj, b_proj, nullptr, out, mf);
}